// Round 3
// baseline (999.413 us; speedup 1.0000x reference)
//
#include <hip/hip_runtime.h>

typedef unsigned short u16;
typedef short s16x8 __attribute__((ext_vector_type(8)));
typedef float f32x4 __attribute__((ext_vector_type(4)));

#define DEVI static __device__ __forceinline__
#define MFMA16(A, B, C) __builtin_amdgcn_mfma_f32_16x16x32_bf16(A, B, C, 0, 0, 0)
#define Z4 ((f32x4){0.f, 0.f, 0.f, 0.f})

DEVI float bf2f(u16 u) {
  unsigned int x = ((unsigned int)u) << 16;
  float f; __builtin_memcpy(&f, &x, 4); return f;
}
DEVI u16 f2bf(float f) {
  unsigned int u; __builtin_memcpy(&u, &f, 4);
  u += 0x7fffu + ((u >> 16) & 1u);
  return (u16)(u >> 16);
}
DEVI float sigmoidf_(float x) { return 1.0f / (1.0f + __expf(-x)); }
DEVI float tanhf_(float x) { return 1.0f - 2.0f / (__expf(2.0f * x) + 1.0f); }

// ---------------- merged weight f32 -> bf16 ----------------
// dst layout: Wproj@0 | Wout@196608 | Wlin@262144 | Wih@327680 | Whh@524288
__global__ void k_wconv(const float* __restrict__ w0, const float* __restrict__ w1,
                        const float* __restrict__ w2, const float* __restrict__ w3,
                        const float* __restrict__ w4, u16* __restrict__ out) {
  int i = blockIdx.x * 256 + threadIdx.x;
  if (i >= 720896) return;
  const float* src; int off;
  if (i < 196608) { src = w0; off = i; }
  else if (i < 262144) { src = w1; off = i - 196608; }
  else if (i < 327680) { src = w2; off = i - 262144; }
  else if (i < 524288) { src = w3; off = i - 327680; }
  else { src = w4; off = i - 524288; }
  out[i] = f2bf(src[off]);
}

// =================================================================
// Phase 1: fused  QKV-proj -> QK^T -> softmax -> PV -> out-proj
// One block per n (2048 blocks), 512 threads (8 waves).
// Math note: channel/spatial attention collapse to identity
// (softmax over size-1 axes == 1), so fused = 2*input exactly.
// LDS overlay plan (u16 offsets), total 40704 u16 = 79.5 KB -> 2 blocks/CU:
//   pass1:  QB [2][32][264] @0, KB [2][32][264] @16896   (Q,K live a->b)
//   scores: SF f32[2][32][34] @33792 (bytes 67584..76288; disjoint from QB/KB)
//   pass2:  VT [2][256][40] @0 (overlays dead Q/K), OB [2][32][264] @20480,
//           PB [2][32][40] @38144
// =================================================================
#define QB 0
#define KBo 16896
#define VTo 0
#define OBo 20480
#define SFo 33792
#define PBo 38144

__global__ __launch_bounds__(512, 4) void k_attn(
    const float* __restrict__ text, const float* __restrict__ graph,
    const u16* __restrict__ Wproj, const float* __restrict__ bproj,
    const u16* __restrict__ Wout, const float* __restrict__ bout,
    u16* __restrict__ attT, u16* __restrict__ attG) {
  __shared__ u16 sh[40704];
  int n = blockIdx.x;
  int tid = threadIdx.x;
  int w = tid >> 6, lane = tid & 63;
  int lr = lane & 15, kg = lane >> 4;
  int sw = w >> 2, wq = w & 3;

  // ---- A-fragments for this wave's side (rows mt*16+lr, all K) ----
  const float* inS = sw ? graph : text;
  s16x8 aS[2][8];
#pragma unroll
  for (int mt = 0; mt < 2; ++mt)
#pragma unroll
    for (int k = 0; k < 8; ++k) {
      const float* p = inS + ((mt * 16 + lr) * 2048 + n) * 256 + k * 32 + kg * 8;
      f32x4 v0 = *(const f32x4*)p;
      f32x4 v1 = *(const f32x4*)(p + 4);
      s16x8 t;
      t[0] = (short)f2bf(2.f * v0[0]); t[1] = (short)f2bf(2.f * v0[1]);
      t[2] = (short)f2bf(2.f * v0[2]); t[3] = (short)f2bf(2.f * v0[3]);
      t[4] = (short)f2bf(2.f * v1[0]); t[5] = (short)f2bf(2.f * v1[1]);
      t[6] = (short)f2bf(2.f * v1[2]); t[7] = (short)f2bf(2.f * v1[3]);
      aS[mt][k] = t;
    }

  // ---- pass 1: Q,K projection (cols 0..511), 8 tiles/wave ----
  for (int i = 0; i < 8; ++i) {
    int col0 = (wq * 8 + i) * 16;
    int col = col0 + lr;
    const u16* wp = Wproj + col * 256 + kg * 8;
    s16x8 b[8];
#pragma unroll
    for (int k = 0; k < 8; ++k) b[k] = *(const s16x8*)(wp + k * 32);
    f32x4 a0 = Z4, a1 = Z4;
#pragma unroll
    for (int k = 0; k < 8; ++k) {
      a0 = MFMA16(aS[0][k], b[k], a0);
      a1 = MFMA16(aS[1][k], b[k], a1);
    }
    float bias = bproj[col];
    u16* base = sh + (col < 256 ? (QB + sw * 8448 + col) : (KBo + sw * 8448 + col - 256));
#pragma unroll
    for (int j = 0; j < 4; ++j) {
      base[(kg * 4 + j) * 264] = f2bf(a0[j] + bias);
      base[(16 + kg * 4 + j) * 264] = f2bf(a1[j] + bias);
    }
  }
  __syncthreads();

  // ---- scores: S_s = Q_s . K_{1-s}^T / 16 ----
  {
    int s = sw, mt = (w >> 1) & 1, nt = w & 1;
    f32x4 acc = Z4;
#pragma unroll
    for (int k = 0; k < 8; ++k) {
      s16x8 qa = *(const s16x8*)(sh + QB + s * 8448 + (mt * 16 + lr) * 264 + k * 32 + kg * 8);
      s16x8 kb = *(const s16x8*)(sh + KBo + (1 - s) * 8448 + (nt * 16 + lr) * 264 + k * 32 + kg * 8);
      acc = MFMA16(qa, kb, acc);
    }
    float* SF = (float*)(sh + SFo) + s * 1088;
#pragma unroll
    for (int j = 0; j < 4; ++j)
      SF[(mt * 16 + kg * 4 + j) * 34 + nt * 16 + lr] = acc[j] * 0.0625f;
  }
  __syncthreads();

  // ---- pass 2: V projection (cols 512..767) into VT (overlays dead Q/K) ----
  for (int i = 0; i < 4; ++i) {
    int col0 = 512 + (wq * 4 + i) * 16;
    int col = col0 + lr;
    const u16* wp = Wproj + col * 256 + kg * 8;
    s16x8 b[8];
#pragma unroll
    for (int k = 0; k < 8; ++k) b[k] = *(const s16x8*)(wp + k * 32);
    f32x4 a0 = Z4, a1 = Z4;
#pragma unroll
    for (int k = 0; k < 8; ++k) {
      a0 = MFMA16(aS[0][k], b[k], a0);
      a1 = MFMA16(aS[1][k], b[k], a1);
    }
    float bias = bproj[col];
    u16* base = sh + VTo + sw * 10240 + (col - 512) * 40;
#pragma unroll
    for (int j = 0; j < 4; ++j) {
      base[kg * 4 + j] = f2bf(a0[j] + bias);
      base[16 + kg * 4 + j] = f2bf(a1[j] + bias);
    }
  }
  // ---- softmax (wave 0; SF region is disjoint from VT writes) ----
  if (tid < 64) {
    int s = tid >> 5, l = tid & 31;
    float* Sp = (float*)(sh + SFo) + s * 1088 + l * 34;
    float mx = -1e30f;
#pragma unroll
    for (int m = 0; m < 32; ++m) mx = fmaxf(mx, Sp[m]);
    float e[32]; float sum = 0.f;
#pragma unroll
    for (int m = 0; m < 32; ++m) { e[m] = __expf(Sp[m] - mx); sum += e[m]; }
    float inv = 1.f / sum;
    u16* Pp = sh + PBo + s * 1280 + l * 40;
#pragma unroll
    for (int m = 0; m < 32; ++m) Pp[m] = f2bf(e[m] * inv);
  }
  __syncthreads();

  // ---- PV: O_s = P_s . V_s  -> OB ----
  {
    s16x8 pa0 = *(const s16x8*)(sh + PBo + sw * 1280 + lr * 40 + kg * 8);
    s16x8 pa1 = *(const s16x8*)(sh + PBo + sw * 1280 + (16 + lr) * 40 + kg * 8);
#pragma unroll
    for (int i = 0; i < 4; ++i) {
      int e0 = (wq * 4 + i) * 16;
      s16x8 vb = *(const s16x8*)(sh + VTo + sw * 10240 + (e0 + lr) * 40 + kg * 8);
      f32x4 a0 = MFMA16(pa0, vb, Z4);
      f32x4 a1 = MFMA16(pa1, vb, Z4);
      u16* base = sh + OBo + sw * 8448 + e0 + lr;
#pragma unroll
      for (int j = 0; j < 4; ++j) {
        base[(kg * 4 + j) * 264] = f2bf(a0[j]);
        base[(16 + kg * 4 + j) * 264] = f2bf(a1[j]);
      }
    }
  }
  __syncthreads();

  // ---- out-proj: att_s = O_s @ Wout^T + bout -> global bf16 ----
  {
    s16x8 aO[2][8];
#pragma unroll
    for (int mt = 0; mt < 2; ++mt)
#pragma unroll
      for (int k = 0; k < 8; ++k)
        aO[mt][k] = *(const s16x8*)(sh + OBo + sw * 8448 + (mt * 16 + lr) * 264 + k * 32 + kg * 8);
    u16* dst = sw ? attG : attT;
#pragma unroll
    for (int i = 0; i < 4; ++i) {
      int colb = (wq * 4 + i) * 16;
      const u16* wp = Wout + (colb + lr) * 256 + kg * 8;
      s16x8 b[8];
#pragma unroll
      for (int k = 0; k < 8; ++k) b[k] = *(const s16x8*)(wp + k * 32);
      f32x4 a0 = Z4, a1 = Z4;
#pragma unroll
      for (int k = 0; k < 8; ++k) {
        a0 = MFMA16(aO[0][k], b[k], a0);
        a1 = MFMA16(aO[1][k], b[k], a1);
      }
      int cb = colb + lr;
      float bias = bout[cb];
#pragma unroll
      for (int j = 0; j < 4; ++j) {
        dst[((long)(kg * 4 + j) * 2048 + n) * 256 + cb] = f2bf(a0[j] + bias);
        dst[((long)(16 + kg * 4 + j) * 2048 + n) * 256 + cb] = f2bf(a1[j] + bias);
      }
    }
  }
}

// =================================================================
// Phase 2: fused  H=attT*attG -> inter=H@Wlin^T -> gi/gh1/gh2 -> GRU
// One block per 64 rows (1024 blocks), 512 threads (8 waves).
// wave: rows (w&3)*16, col-half (w>>2)*128.
// LDS: inter exchange buffer only: [64][264] u16 = 33.8 KB -> 2 blocks/CU.
// attT/attG re-read from global (per-block footprint 64KB, L2-hot).
// =================================================================
__global__ __launch_bounds__(512, 4) void k_gru(
    const u16* __restrict__ attT, const u16* __restrict__ attG,
    const u16* __restrict__ Wlin, const float* __restrict__ blin,
    const u16* __restrict__ Wih, const float* __restrict__ bih,
    const u16* __restrict__ Whh, const float* __restrict__ bhh,
    u16* __restrict__ g1, u16* __restrict__ g2) {
  __shared__ u16 HI[64 * 264];
  long m0 = (long)blockIdx.x * 64;
  int tid = threadIdx.x, w = tid >> 6, lane = tid & 63;
  int lr = lane & 15, kg = lane >> 4;
  int rw = (w & 3) * 16, ch = w >> 2;

  // phase 1: H fragments (product computed on the fly, f32 -> bf16)
  s16x8 aH[8];
#pragma unroll
  for (int k = 0; k < 8; ++k) {
    const u16* pt = attT + (m0 + rw + lr) * 256 + k * 32 + kg * 8;
    const u16* pg = attG + (m0 + rw + lr) * 256 + k * 32 + kg * 8;
    s16x8 t8 = *(const s16x8*)pt;
    s16x8 g8 = *(const s16x8*)pg;
    s16x8 h;
#pragma unroll
    for (int j = 0; j < 8; ++j)
      h[j] = (short)f2bf(bf2f((u16)t8[j]) * bf2f((u16)g8[j]));
    aH[k] = h;
  }

  // phase 2: inter = H @ Wlin^T + blin -> LDS
  for (int i = 0; i < 8; ++i) {
    int colb = (ch * 8 + i) * 16;
    const u16* wp = Wlin + (colb + lr) * 256 + kg * 8;
    s16x8 b[8];
#pragma unroll
    for (int k = 0; k < 8; ++k) b[k] = *(const s16x8*)(wp + k * 32);
    f32x4 acc = Z4;
#pragma unroll
    for (int k = 0; k < 8; ++k) acc = MFMA16(aH[k], b[k], acc);
    float bias = blin[colb + lr];
    u16* base = HI + colb + lr;
#pragma unroll
    for (int j = 0; j < 4; ++j)
      base[(rw + kg * 4 + j) * 264] = f2bf(acc[j] + bias);
  }
  __syncthreads();

  // phase 3: gate GEMMs + GRU elementwise
  s16x8 aT8[8], aG8[8];
#pragma unroll
  for (int k = 0; k < 8; ++k) {
    aT8[k] = *(const s16x8*)(attT + (m0 + rw + lr) * 256 + k * 32 + kg * 8);
    aG8[k] = *(const s16x8*)(attG + (m0 + rw + lr) * 256 + k * 32 + kg * 8);
  }
  for (int ic = 0; ic < 8; ++ic) {
    int col = (ch * 8 + ic) * 16 + lr;
    f32x4 acc[3][3];
#pragma unroll
    for (int g = 0; g < 3; ++g)
#pragma unroll
      for (int s2 = 0; s2 < 3; ++s2) acc[g][s2] = Z4;
#pragma unroll
    for (int k = 0; k < 8; ++k) {
      s16x8 aI = *(const s16x8*)(HI + (rw + lr) * 264 + k * 32 + kg * 8);
#pragma unroll
      for (int g = 0; g < 3; ++g) {
        s16x8 bI = *(const s16x8*)(Wih + (g * 256 + col) * 256 + k * 32 + kg * 8);
        s16x8 bH = *(const s16x8*)(Whh + (g * 256 + col) * 256 + k * 32 + kg * 8);
        acc[g][0] = MFMA16(aI, bI, acc[g][0]);
        acc[g][1] = MFMA16(aT8[k], bH, acc[g][1]);
        acc[g][2] = MFMA16(aG8[k], bH, acc[g][2]);
      }
    }
    float bir = bih[col], biz = bih[col + 256], bin = bih[col + 512];
    float bhr = bhh[col], bhz = bhh[col + 256], bhn = bhh[col + 512];
#pragma unroll
    for (int j = 0; j < 4; ++j) {
      int row = rw + kg * 4 + j;
      long off = (m0 + row) * 256 + col;
      float hT = bf2f(attT[off]);
      float hG = bf2f(attG[off]);
      float ir = acc[0][0][j] + bir;
      float iz = acc[1][0][j] + biz;
      float inn = acc[2][0][j] + bin;
      float r1 = sigmoidf_(ir + acc[0][1][j] + bhr);
      float z1 = sigmoidf_(iz + acc[1][1][j] + bhz);
      float n1 = tanhf_(inn + r1 * (acc[2][1][j] + bhn));
      float o1 = (1.f - z1) * n1 + z1 * hT;
      float r2 = sigmoidf_(ir + acc[0][2][j] + bhr);
      float z2 = sigmoidf_(iz + acc[1][2][j] + bhz);
      float n2 = tanhf_(inn + r2 * (acc[2][2][j] + bhn));
      float o2 = (1.f - z2) * n2 + z2 * hG;
      g1[off] = f2bf(o1);
      g2[off] = f2bf(o2);
    }
  }
}

// =================================================================
// Phase 3: out = relu(conv7x7(g1)+b) + relu(conv7x7(g2)+b), f32 out
// =================================================================
__global__ __launch_bounds__(256) void k_conv(
    const u16* __restrict__ g1, const u16* __restrict__ g2,
    const float* __restrict__ wss, const float* __restrict__ bss,
    float* __restrict__ out) {
  __shared__ float s1[38][73];
  __shared__ float s2[38][73];
  int et = blockIdx.x, st = blockIdx.y, b = blockIdx.z;
  int s0 = st * 32, e0 = et * 64;
  int tid = threadIdx.x;
  for (int idx = tid; idx < 38 * 70; idx += 256) {
    int r = idx / 70, c = idx % 70;
    int s = s0 + r - 3, e = e0 + c - 3;
    float v1 = 0.f, v2 = 0.f;
    if (s >= 0 && s < 2048 && e >= 0 && e < 256) {
      long off = ((long)b * 2048 + s) * 256 + e;
      v1 = bf2f(g1[off]); v2 = bf2f(g2[off]);
    }
    s1[r][c] = v1; s2[r][c] = v2;
  }
  __syncthreads();
  float bias = bss[0];
  int oy = tid >> 3, ox = (tid & 7) * 8;
  float a1[8] = {0.f, 0.f, 0.f, 0.f, 0.f, 0.f, 0.f, 0.f};
  float a2[8] = {0.f, 0.f, 0.f, 0.f, 0.f, 0.f, 0.f, 0.f};
#pragma unroll
  for (int ky = 0; ky < 7; ++ky) {
    float wr[7];
#pragma unroll
    for (int kx = 0; kx < 7; ++kx) wr[kx] = wss[ky * 7 + kx];
    float r1[14], r2[14];
#pragma unroll
    for (int j = 0; j < 14; ++j) { r1[j] = s1[oy + ky][ox + j]; r2[j] = s2[oy + ky][ox + j]; }
#pragma unroll
    for (int x = 0; x < 8; ++x)
#pragma unroll
      for (int kx = 0; kx < 7; ++kx) {
        a1[x] += r1[x + kx] * wr[kx];
        a2[x] += r2[x + kx] * wr[kx];
      }
  }
  long obase = ((long)b * 2048 + s0 + oy) * 256 + e0 + ox;
  f32x4 o0, o1;
#pragma unroll
  for (int x = 0; x < 4; ++x) {
    o0[x] = fmaxf(a1[x] + bias, 0.f) + fmaxf(a2[x] + bias, 0.f);
    o1[x] = fmaxf(a1[x + 4] + bias, 0.f) + fmaxf(a2[x + 4] + bias, 0.f);
  }
  *(f32x4*)(out + obase) = o0;
  *(f32x4*)(out + obase + 4) = o1;
}

extern "C" void kernel_launch(void* const* d_in, const int* in_sizes, int n_in,
                              void* d_out, int out_size, void* d_ws, size_t ws_size,
                              hipStream_t stream) {
  const float* text = (const float*)d_in[0];
  const float* graph = (const float*)d_in[1];
  // d_in[2..7] (avg_*/max_*/sp_*) are mathematically dead:
  // softmax over size-1 axes == 1 -> fused = 2*input exactly.
  const float* in_proj_w = (const float*)d_in[8];
  const float* in_proj_b = (const float*)d_in[9];
  const float* out_w = (const float*)d_in[10];
  const float* out_b = (const float*)d_in[11];
  const float* lin_w = (const float*)d_in[12];
  const float* lin_b = (const float*)d_in[13];
  const float* w_ih = (const float*)d_in[14];
  const float* w_hh = (const float*)d_in[15];
  const float* b_ih = (const float*)d_in[16];
  const float* b_hh = (const float*)d_in[17];
  const float* ssf_w = (const float*)d_in[18];
  const float* ssf_b = (const float*)d_in[19];

  // ws: g1 (32MB) | g2 (32MB) | bf16 weights (~1.4MB)
  u16* g1 = (u16*)d_ws;
  u16* g2 = g1 + 16777216;
  u16* Wall = g2 + 16777216;
  u16* Wproj = Wall;
  u16* Wout = Wall + 196608;
  u16* Wlin = Wall + 262144;
  u16* Wih = Wall + 327680;
  u16* Whh = Wall + 524288;

  // d_out (64MB f32) doubles as bf16 scratch for attT/attG;
  // k_conv fully rewrites it as f32 at the end.
  u16* attT = (u16*)d_out;
  u16* attG = attT + 16777216;

  k_wconv<<<2816, 256, 0, stream>>>(in_proj_w, out_w, lin_w, w_ih, w_hh, Wall);

  k_attn<<<2048, 512, 0, stream>>>(text, graph, Wproj, in_proj_b, Wout, out_b, attT, attG);
  k_gru<<<1024, 512, 0, stream>>>(attT, attG, Wlin, lin_b, Wih, b_ih, Whh, b_hh, g1, g2);
  k_conv<<<dim3(4, 64, 32), 256, 0, stream>>>(g1, g2, ssf_w, ssf_b, (float*)d_out);
}

// Round 4
// 928.511 us; speedup vs baseline: 1.0764x; 1.0764x over previous
//
#include <hip/hip_runtime.h>

typedef unsigned short u16;
typedef short s16x8 __attribute__((ext_vector_type(8)));
typedef float f32x4 __attribute__((ext_vector_type(4)));

#define DEVI static __device__ __forceinline__
#define MFMA16(A, B, C) __builtin_amdgcn_mfma_f32_16x16x32_bf16(A, B, C, 0, 0, 0)
#define Z4 ((f32x4){0.f, 0.f, 0.f, 0.f})

DEVI float bf2f(u16 u) {
  unsigned int x = ((unsigned int)u) << 16;
  float f; __builtin_memcpy(&f, &x, 4); return f;
}
DEVI u16 f2bf(float f) {
  unsigned int u; __builtin_memcpy(&u, &f, 4);
  u += 0x7fffu + ((u >> 16) & 1u);
  return (u16)(u >> 16);
}
DEVI float sigmoidf_(float x) { return 1.0f / (1.0f + __expf(-x)); }
DEVI float tanhf_(float x) { return 1.0f - 2.0f / (__expf(2.0f * x) + 1.0f); }

// ---------------- merged weight f32 -> bf16 ----------------
__global__ void k_wconv(const float* __restrict__ w0, const float* __restrict__ w1,
                        const float* __restrict__ w2, const float* __restrict__ w3,
                        const float* __restrict__ w4, u16* __restrict__ out) {
  int i = blockIdx.x * 256 + threadIdx.x;
  if (i >= 720896) return;
  const float* src; int off;
  if (i < 196608) { src = w0; off = i; }
  else if (i < 262144) { src = w1; off = i - 196608; }
  else if (i < 327680) { src = w2; off = i - 262144; }
  else if (i < 524288) { src = w3; off = i - 327680; }
  else { src = w4; off = i - 524288; }
  out[i] = f2bf(src[off]);
}

// =================================================================
// Phase 1: one block per (n, side): Q_s, K_{1-s}, V_s proj -> scores
// -> softmax -> PV -> out-proj. 4096 blocks x 256 thr (4 waves).
// Math note: channel/spatial attention collapse to identity
// (softmax over size-1 axes == 1), so fused = 2*input exactly.
// LDS overlay (u16 offsets), 44.3 KB -> 3 blocks/CU:
//  phase1: QB[32][264]@0, KB[32][264]@8448
//  phase2 (Q,K dead): VT[256][40]@0, OB[32][264]@10240
//  SF f32[32][34]@18688, PB[32][40]@20864 ; total 22144 u16
// =================================================================
#define QBo 0
#define KBo 8448
#define VTo 0
#define OBo 10240
#define SFo 18688
#define PBo 20864

__global__ __launch_bounds__(256, 3) void k_attn(
    const float* __restrict__ text, const float* __restrict__ graph,
    const u16* __restrict__ Wproj, const float* __restrict__ bproj,
    const u16* __restrict__ Wout, const float* __restrict__ bout,
    u16* __restrict__ attT, u16* __restrict__ attG) {
  __shared__ u16 sh[22144];
  int n = blockIdx.x;
  int s = blockIdx.y;
  const float* own = s ? graph : text;
  const float* oth = s ? text : graph;
  u16* dst = s ? attG : attT;
  int tid = threadIdx.x;
  int w = tid >> 6, lane = tid & 63, lr = lane & 15, kg = lane >> 4;

  // ---- K_{1-s} projection (cols 256..511 of Wproj), A = 2*oth ----
  {
    s16x8 aO[2][8];
#pragma unroll
    for (int mt = 0; mt < 2; ++mt)
#pragma unroll
      for (int k = 0; k < 8; ++k) {
        const float* p = oth + ((mt * 16 + lr) * 2048 + n) * 256 + k * 32 + kg * 8;
        f32x4 v0 = *(const f32x4*)p;
        f32x4 v1 = *(const f32x4*)(p + 4);
        s16x8 t;
        t[0] = (short)f2bf(2.f * v0[0]); t[1] = (short)f2bf(2.f * v0[1]);
        t[2] = (short)f2bf(2.f * v0[2]); t[3] = (short)f2bf(2.f * v0[3]);
        t[4] = (short)f2bf(2.f * v1[0]); t[5] = (short)f2bf(2.f * v1[1]);
        t[6] = (short)f2bf(2.f * v1[2]); t[7] = (short)f2bf(2.f * v1[3]);
        aO[mt][k] = t;
      }
    for (int i = 0; i < 4; ++i) {
      int col0 = 256 + (w * 4 + i) * 16;
      int col = col0 + lr;
      const u16* wp = Wproj + col * 256 + kg * 8;
      s16x8 b[8];
#pragma unroll
      for (int k = 0; k < 8; ++k) b[k] = *(const s16x8*)(wp + k * 32);
      f32x4 a0 = Z4, a1 = Z4;
#pragma unroll
      for (int k = 0; k < 8; ++k) {
        a0 = MFMA16(aO[0][k], b[k], a0);
        a1 = MFMA16(aO[1][k], b[k], a1);
      }
      float bias = bproj[col];
      u16* base = sh + KBo + (col - 256);
#pragma unroll
      for (int j = 0; j < 4; ++j) {
        base[(kg * 4 + j) * 264] = f2bf(a0[j] + bias);
        base[(16 + kg * 4 + j) * 264] = f2bf(a1[j] + bias);
      }
    }
  }

  // ---- own-side A fragments (live through Q and V projections) ----
  s16x8 aS[2][8];
#pragma unroll
  for (int mt = 0; mt < 2; ++mt)
#pragma unroll
    for (int k = 0; k < 8; ++k) {
      const float* p = own + ((mt * 16 + lr) * 2048 + n) * 256 + k * 32 + kg * 8;
      f32x4 v0 = *(const f32x4*)p;
      f32x4 v1 = *(const f32x4*)(p + 4);
      s16x8 t;
      t[0] = (short)f2bf(2.f * v0[0]); t[1] = (short)f2bf(2.f * v0[1]);
      t[2] = (short)f2bf(2.f * v0[2]); t[3] = (short)f2bf(2.f * v0[3]);
      t[4] = (short)f2bf(2.f * v1[0]); t[5] = (short)f2bf(2.f * v1[1]);
      t[6] = (short)f2bf(2.f * v1[2]); t[7] = (short)f2bf(2.f * v1[3]);
      aS[mt][k] = t;
    }

  // ---- Q_s projection (cols 0..255) ----
  for (int i = 0; i < 4; ++i) {
    int col0 = (w * 4 + i) * 16;
    int col = col0 + lr;
    const u16* wp = Wproj + col * 256 + kg * 8;
    s16x8 b[8];
#pragma unroll
    for (int k = 0; k < 8; ++k) b[k] = *(const s16x8*)(wp + k * 32);
    f32x4 a0 = Z4, a1 = Z4;
#pragma unroll
    for (int k = 0; k < 8; ++k) {
      a0 = MFMA16(aS[0][k], b[k], a0);
      a1 = MFMA16(aS[1][k], b[k], a1);
    }
    float bias = bproj[col];
    u16* base = sh + QBo + col;
#pragma unroll
    for (int j = 0; j < 4; ++j) {
      base[(kg * 4 + j) * 264] = f2bf(a0[j] + bias);
      base[(16 + kg * 4 + j) * 264] = f2bf(a1[j] + bias);
    }
  }
  __syncthreads();

  // ---- scores S[q][m] = Q . K^T / 16 (each wave one 16x16 tile) ----
  {
    int mt = w >> 1, nt = w & 1;
    f32x4 acc = Z4;
#pragma unroll
    for (int k = 0; k < 8; ++k) {
      s16x8 qa = *(const s16x8*)(sh + QBo + (mt * 16 + lr) * 264 + k * 32 + kg * 8);
      s16x8 kb = *(const s16x8*)(sh + KBo + (nt * 16 + lr) * 264 + k * 32 + kg * 8);
      acc = MFMA16(qa, kb, acc);
    }
    float* SF = (float*)(sh + SFo);
#pragma unroll
    for (int j = 0; j < 4; ++j)
      SF[(mt * 16 + kg * 4 + j) * 34 + nt * 16 + lr] = acc[j] * 0.0625f;
  }
  __syncthreads();

  // ---- V proj (waves 1-3, overlays dead Q/K) + softmax (wave 0) ----
  if (w == 0) {
    if (lane < 32) {
      float* Sp = (float*)(sh + SFo) + lane * 34;
      float mx = -1e30f;
#pragma unroll
      for (int m = 0; m < 32; ++m) mx = fmaxf(mx, Sp[m]);
      float sum = 0.f;
#pragma unroll
      for (int m = 0; m < 32; ++m) { float e = __expf(Sp[m] - mx); Sp[m] = e; sum += e; }
      float inv = 1.f / sum;
      u16* Pp = sh + PBo + lane * 40;
#pragma unroll
      for (int m = 0; m < 32; ++m) Pp[m] = f2bf(Sp[m] * inv);
    }
  } else {
    int t0 = (w - 1) * 6, t1 = (w == 3) ? 16 : t0 + 6;
    for (int t = t0; t < t1; ++t) {
      int col0 = 512 + t * 16;
      int col = col0 + lr;
      const u16* wp = Wproj + col * 256 + kg * 8;
      s16x8 b[8];
#pragma unroll
      for (int k = 0; k < 8; ++k) b[k] = *(const s16x8*)(wp + k * 32);
      f32x4 a0 = Z4, a1 = Z4;
#pragma unroll
      for (int k = 0; k < 8; ++k) {
        a0 = MFMA16(aS[0][k], b[k], a0);
        a1 = MFMA16(aS[1][k], b[k], a1);
      }
      float bias = bproj[col];
      u16* base = sh + VTo + (col - 512) * 40;
#pragma unroll
      for (int j = 0; j < 4; ++j) {
        base[kg * 4 + j] = f2bf(a0[j] + bias);
        base[16 + kg * 4 + j] = f2bf(a1[j] + bias);
      }
    }
  }
  __syncthreads();

  // ---- PV: O = P . V -> OB ----
  {
    s16x8 pa0 = *(const s16x8*)(sh + PBo + lr * 40 + kg * 8);
    s16x8 pa1 = *(const s16x8*)(sh + PBo + (16 + lr) * 40 + kg * 8);
#pragma unroll
    for (int i = 0; i < 4; ++i) {
      int e0 = (w * 4 + i) * 16;
      s16x8 vb = *(const s16x8*)(sh + VTo + (e0 + lr) * 40 + kg * 8);
      f32x4 a0 = MFMA16(pa0, vb, Z4);
      f32x4 a1 = MFMA16(pa1, vb, Z4);
      u16* base = sh + OBo + e0 + lr;
#pragma unroll
      for (int j = 0; j < 4; ++j) {
        base[(kg * 4 + j) * 264] = f2bf(a0[j]);
        base[(16 + kg * 4 + j) * 264] = f2bf(a1[j]);
      }
    }
  }
  __syncthreads();

  // ---- out-proj, staged through OB for coalesced global writes ----
  {
    s16x8 aO[2][8];
#pragma unroll
    for (int mt = 0; mt < 2; ++mt)
#pragma unroll
      for (int k = 0; k < 8; ++k)
        aO[mt][k] = *(const s16x8*)(sh + OBo + (mt * 16 + lr) * 264 + k * 32 + kg * 8);
    f32x4 d0[4], d1[4];
#pragma unroll
    for (int i = 0; i < 4; ++i) {
      int colb = (w * 4 + i) * 16;
      const u16* wp = Wout + (colb + lr) * 256 + kg * 8;
      s16x8 b[8];
#pragma unroll
      for (int k = 0; k < 8; ++k) b[k] = *(const s16x8*)(wp + k * 32);
      f32x4 a0 = Z4, a1 = Z4;
#pragma unroll
      for (int k = 0; k < 8; ++k) {
        a0 = MFMA16(aO[0][k], b[k], a0);
        a1 = MFMA16(aO[1][k], b[k], a1);
      }
      float bias = bout[colb + lr];
#pragma unroll
      for (int j = 0; j < 4; ++j) { a0[j] += bias; a1[j] += bias; }
      d0[i] = a0; d1[i] = a1;
    }
    __syncthreads();  // all OB fragment reads done
#pragma unroll
    for (int i = 0; i < 4; ++i) {
      int cb = (w * 4 + i) * 16 + lr;
      u16* base = sh + OBo + cb;
#pragma unroll
      for (int j = 0; j < 4; ++j) {
        base[(kg * 4 + j) * 264] = f2bf(d0[i][j]);
        base[(16 + kg * 4 + j) * 264] = f2bf(d1[i][j]);
      }
    }
    __syncthreads();
    int r = tid >> 3, c = (tid & 7) * 32;
    u16* drow = dst + ((long)r * 2048 + n) * 256 + c;
#pragma unroll
    for (int j = 0; j < 4; ++j)
      *(s16x8*)(drow + j * 8) = *(const s16x8*)(sh + OBo + r * 264 + c + j * 8);
  }
}

// =================================================================
// Phase 2: fused H -> inter -> gates -> GRU. 2048 blocks (32 rows),
// 256 thr (4 waves); wave = 32 rows x 64 cols (2 M-tiles per B-frag).
// LDS: AT[32][264]@0, AG@8448, HI@16896 = 49.5 KB -> 3 blocks/CU.
// =================================================================
__global__ __launch_bounds__(256, 3) void k_gru(
    const u16* __restrict__ attT, const u16* __restrict__ attG,
    const u16* __restrict__ Wlin, const float* __restrict__ blin,
    const u16* __restrict__ Wih, const float* __restrict__ bih,
    const u16* __restrict__ Whh, const float* __restrict__ bhh,
    u16* __restrict__ g1, u16* __restrict__ g2) {
  __shared__ u16 sh[25344];
  const int AT = 0, AG = 8448, HI = 16896;
  long m0 = (long)blockIdx.x * 32;
  int tid = threadIdx.x, w = tid >> 6, lane = tid & 63;
  int lr = lane & 15, kg = lane >> 4;

  // cooperative load of att rows (fully coalesced)
  {
    int r = tid >> 3, c0 = (tid & 7) * 32;
    const u16* pt = attT + (m0 + r) * 256 + c0;
    const u16* pg = attG + (m0 + r) * 256 + c0;
#pragma unroll
    for (int j = 0; j < 4; ++j) {
      *(s16x8*)(sh + AT + r * 264 + c0 + j * 8) = *(const s16x8*)(pt + j * 8);
      *(s16x8*)(sh + AG + r * 264 + c0 + j * 8) = *(const s16x8*)(pg + j * 8);
    }
  }
  __syncthreads();

  // H fragments (product of att pair, bf16)
  s16x8 aH[2][8];
#pragma unroll
  for (int mt = 0; mt < 2; ++mt)
#pragma unroll
    for (int k = 0; k < 8; ++k) {
      s16x8 t8 = *(const s16x8*)(sh + AT + (mt * 16 + lr) * 264 + k * 32 + kg * 8);
      s16x8 g8 = *(const s16x8*)(sh + AG + (mt * 16 + lr) * 264 + k * 32 + kg * 8);
      s16x8 h;
#pragma unroll
      for (int j = 0; j < 8; ++j)
        h[j] = (short)f2bf(bf2f((u16)t8[j]) * bf2f((u16)g8[j]));
      aH[mt][k] = h;
    }

  // inter = H @ Wlin^T + blin -> HI
  for (int i = 0; i < 4; ++i) {
    int col = w * 64 + i * 16 + lr;
    const u16* wp = Wlin + col * 256 + kg * 8;
    s16x8 b[8];
#pragma unroll
    for (int k = 0; k < 8; ++k) b[k] = *(const s16x8*)(wp + k * 32);
    f32x4 a0 = Z4, a1 = Z4;
#pragma unroll
    for (int k = 0; k < 8; ++k) {
      a0 = MFMA16(aH[0][k], b[k], a0);
      a1 = MFMA16(aH[1][k], b[k], a1);
    }
    float bias = blin[col];
    u16* base = sh + HI + col;
#pragma unroll
    for (int j = 0; j < 4; ++j) {
      base[(kg * 4 + j) * 264] = f2bf(a0[j] + bias);
      base[(16 + kg * 4 + j) * 264] = f2bf(a1[j] + bias);
    }
  }
  __syncthreads();

  // gate GEMMs + GRU elementwise; outputs buffered in regs
  s16x8 o1b[4], o2b[4];
#pragma unroll
  for (int i = 0; i < 4; ++i) {
    int col = w * 64 + i * 16 + lr;
    f32x4 acc[3][3][2];  // [gate][src I/T/G][mt]
#pragma unroll
    for (int g = 0; g < 3; ++g)
#pragma unroll
      for (int s2 = 0; s2 < 3; ++s2) { acc[g][s2][0] = Z4; acc[g][s2][1] = Z4; }
#pragma unroll
    for (int k = 0; k < 8; ++k) {
      int ko = k * 32 + kg * 8;
      s16x8 aI0 = *(const s16x8*)(sh + HI + lr * 264 + ko);
      s16x8 aI1 = *(const s16x8*)(sh + HI + (16 + lr) * 264 + ko);
      s16x8 aT0 = *(const s16x8*)(sh + AT + lr * 264 + ko);
      s16x8 aT1 = *(const s16x8*)(sh + AT + (16 + lr) * 264 + ko);
      s16x8 aG0 = *(const s16x8*)(sh + AG + lr * 264 + ko);
      s16x8 aG1 = *(const s16x8*)(sh + AG + (16 + lr) * 264 + ko);
#pragma unroll
      for (int g = 0; g < 3; ++g) {
        s16x8 bI = *(const s16x8*)(Wih + (g * 256 + col) * 256 + ko);
        s16x8 bH = *(const s16x8*)(Whh + (g * 256 + col) * 256 + ko);
        acc[g][0][0] = MFMA16(aI0, bI, acc[g][0][0]);
        acc[g][0][1] = MFMA16(aI1, bI, acc[g][0][1]);
        acc[g][1][0] = MFMA16(aT0, bH, acc[g][1][0]);
        acc[g][1][1] = MFMA16(aT1, bH, acc[g][1][1]);
        acc[g][2][0] = MFMA16(aG0, bH, acc[g][2][0]);
        acc[g][2][1] = MFMA16(aG1, bH, acc[g][2][1]);
      }
    }
    float bir = bih[col], biz = bih[col + 256], bin_ = bih[col + 512];
    float bhr = bhh[col], bhz = bhh[col + 256], bhn = bhh[col + 512];
    s16x8 o1v, o2v;
#pragma unroll
    for (int mt = 0; mt < 2; ++mt)
#pragma unroll
      for (int j = 0; j < 4; ++j) {
        int row = mt * 16 + kg * 4 + j;
        float hT = bf2f(sh[AT + row * 264 + col]);
        float hG = bf2f(sh[AG + row * 264 + col]);
        float ir = acc[0][0][mt][j] + bir;
        float iz = acc[1][0][mt][j] + biz;
        float inn = acc[2][0][mt][j] + bin_;
        float r1 = sigmoidf_(ir + acc[0][1][mt][j] + bhr);
        float z1 = sigmoidf_(iz + acc[1][1][mt][j] + bhz);
        float n1 = tanhf_(inn + r1 * (acc[2][1][mt][j] + bhn));
        o1v[mt * 4 + j] = (short)f2bf((1.f - z1) * n1 + z1 * hT);
        float r2 = sigmoidf_(ir + acc[0][2][mt][j] + bhr);
        float z2 = sigmoidf_(iz + acc[1][2][mt][j] + bhz);
        float n2 = tanhf_(inn + r2 * (acc[2][2][mt][j] + bhn));
        o2v[mt * 4 + j] = (short)f2bf((1.f - z2) * n2 + z2 * hG);
      }
    o1b[i] = o1v; o2b[i] = o2v;
  }
  __syncthreads();  // all AT/AG/HI reads done

  // stage outputs into AT/AG, then coalesced contiguous global write
#pragma unroll
  for (int i = 0; i < 4; ++i) {
    int col = w * 64 + i * 16 + lr;
#pragma unroll
    for (int mt = 0; mt < 2; ++mt)
#pragma unroll
      for (int j = 0; j < 4; ++j) {
        int row = mt * 16 + kg * 4 + j;
        sh[AT + row * 264 + col] = (u16)o1b[i][mt * 4 + j];
        sh[AG + row * 264 + col] = (u16)o2b[i][mt * 4 + j];
      }
  }
  __syncthreads();
  {
    int r = tid >> 3, c0 = (tid & 7) * 32;
    u16* p1 = g1 + (m0 << 8) + tid * 32;
    u16* p2 = g2 + (m0 << 8) + tid * 32;
#pragma unroll
    for (int j = 0; j < 4; ++j) {
      *(s16x8*)(p1 + j * 8) = *(const s16x8*)(sh + AT + r * 264 + c0 + j * 8);
      *(s16x8*)(p2 + j * 8) = *(const s16x8*)(sh + AG + r * 264 + c0 + j * 8);
    }
  }
}

// =================================================================
// Phase 3: out = relu(conv7x7(g1)+b) + relu(conv7x7(g2)+b), f32 out
// =================================================================
__global__ __launch_bounds__(256) void k_conv(
    const u16* __restrict__ g1, const u16* __restrict__ g2,
    const float* __restrict__ wss, const float* __restrict__ bss,
    float* __restrict__ out) {
  __shared__ float s1[38][73];
  __shared__ float s2[38][73];
  int et = blockIdx.x, st = blockIdx.y, b = blockIdx.z;
  int s0 = st * 32, e0 = et * 64;
  int tid = threadIdx.x;
  for (int idx = tid; idx < 38 * 70; idx += 256) {
    int r = idx / 70, c = idx % 70;
    int s = s0 + r - 3, e = e0 + c - 3;
    float v1 = 0.f, v2 = 0.f;
    if (s >= 0 && s < 2048 && e >= 0 && e < 256) {
      long off = ((long)b * 2048 + s) * 256 + e;
      v1 = bf2f(g1[off]); v2 = bf2f(g2[off]);
    }
    s1[r][c] = v1; s2[r][c] = v2;
  }
  __syncthreads();
  float bias = bss[0];
  int oy = tid >> 3, ox = (tid & 7) * 8;
  float a1[8] = {0.f, 0.f, 0.f, 0.f, 0.f, 0.f, 0.f, 0.f};
  float a2[8] = {0.f, 0.f, 0.f, 0.f, 0.f, 0.f, 0.f, 0.f};
#pragma unroll
  for (int ky = 0; ky < 7; ++ky) {
    float wr[7];
#pragma unroll
    for (int kx = 0; kx < 7; ++kx) wr[kx] = wss[ky * 7 + kx];
    float r1[14], r2[14];
#pragma unroll
    for (int j = 0; j < 14; ++j) { r1[j] = s1[oy + ky][ox + j]; r2[j] = s2[oy + ky][ox + j]; }
#pragma unroll
    for (int x = 0; x < 8; ++x)
#pragma unroll
      for (int kx = 0; kx < 7; ++kx) {
        a1[x] += r1[x + kx] * wr[kx];
        a2[x] += r2[x + kx] * wr[kx];
      }
  }
  long obase = ((long)b * 2048 + s0 + oy) * 256 + e0 + ox;
  f32x4 o0, o1;
#pragma unroll
  for (int x = 0; x < 4; ++x) {
    o0[x] = fmaxf(a1[x] + bias, 0.f) + fmaxf(a2[x] + bias, 0.f);
    o1[x] = fmaxf(a1[x + 4] + bias, 0.f) + fmaxf(a2[x + 4] + bias, 0.f);
  }
  *(f32x4*)(out + obase) = o0;
  *(f32x4*)(out + obase + 4) = o1;
}

extern "C" void kernel_launch(void* const* d_in, const int* in_sizes, int n_in,
                              void* d_out, int out_size, void* d_ws, size_t ws_size,
                              hipStream_t stream) {
  const float* text = (const float*)d_in[0];
  const float* graph = (const float*)d_in[1];
  // d_in[2..7] (avg_*/max_*/sp_*) are mathematically dead:
  // softmax over size-1 axes == 1 -> fused = 2*input exactly.
  const float* in_proj_w = (const float*)d_in[8];
  const float* in_proj_b = (const float*)d_in[9];
  const float* out_w = (const float*)d_in[10];
  const float* out_b = (const float*)d_in[11];
  const float* lin_w = (const float*)d_in[12];
  const float* lin_b = (const float*)d_in[13];
  const float* w_ih = (const float*)d_in[14];
  const float* w_hh = (const float*)d_in[15];
  const float* b_ih = (const float*)d_in[16];
  const float* b_hh = (const float*)d_in[17];
  const float* ssf_w = (const float*)d_in[18];
  const float* ssf_b = (const float*)d_in[19];

  // ws: g1 (32MB) | g2 (32MB) | bf16 weights (~1.4MB)
  u16* g1 = (u16*)d_ws;
  u16* g2 = g1 + 16777216;
  u16* Wall = g2 + 16777216;
  u16* Wproj = Wall;
  u16* Wout = Wall + 196608;
  u16* Wlin = Wall + 262144;
  u16* Wih = Wall + 327680;
  u16* Whh = Wall + 524288;

  // d_out (64MB f32) doubles as bf16 scratch for attT/attG;
  // k_conv fully rewrites it as f32 at the end.
  u16* attT = (u16*)d_out;
  u16* attG = attT + 16777216;

  k_wconv<<<2816, 256, 0, stream>>>(in_proj_w, out_w, lin_w, w_ih, w_hh, Wall);

  k_attn<<<dim3(2048, 2), 256, 0, stream>>>(text, graph, Wproj, in_proj_b, Wout, out_b, attT, attG);
  k_gru<<<2048, 256, 0, stream>>>(attT, attG, Wlin, lin_b, Wih, b_ih, Whh, b_hh, g1, g2);
  k_conv<<<dim3(4, 64, 32), 256, 0, stream>>>(g1, g2, ssf_w, ssf_b, (float*)d_out);
}

// Round 5
// 737.412 us; speedup vs baseline: 1.3553x; 1.2591x over previous
//
#include <hip/hip_runtime.h>

typedef unsigned short u16;
typedef short s16x8 __attribute__((ext_vector_type(8)));
typedef float f32x4 __attribute__((ext_vector_type(4)));

#define DEVI static __device__ __forceinline__
#define MFMA16(A, B, C) __builtin_amdgcn_mfma_f32_16x16x32_bf16(A, B, C, 0, 0, 0)
#define Z4 ((f32x4){0.f, 0.f, 0.f, 0.f})

DEVI float bf2f(u16 u) {
  unsigned int x = ((unsigned int)u) << 16;
  float f; __builtin_memcpy(&f, &x, 4); return f;
}
DEVI u16 f2bf(float f) {
  unsigned int u; __builtin_memcpy(&u, &f, 4);
  u += 0x7fffu + ((u >> 16) & 1u);
  return (u16)(u >> 16);
}
DEVI float sigmoidf_(float x) { return 1.0f / (1.0f + __expf(-x)); }
DEVI float tanhf_(float x) { return 1.0f - 2.0f / (__expf(2.0f * x) + 1.0f); }

// ---------------- merged weight f32 -> bf16 ----------------
__global__ void k_wconv(const float* __restrict__ w0, const float* __restrict__ w1,
                        const float* __restrict__ w2, const float* __restrict__ w3,
                        const float* __restrict__ w4, u16* __restrict__ out) {
  int i = blockIdx.x * 256 + threadIdx.x;
  if (i >= 720896) return;
  const float* src; int off;
  if (i < 196608) { src = w0; off = i; }
  else if (i < 262144) { src = w1; off = i - 196608; }
  else if (i < 327680) { src = w2; off = i - 262144; }
  else if (i < 524288) { src = w3; off = i - 327680; }
  else { src = w4; off = i - 524288; }
  out[i] = f2bf(src[off]);
}

// =================================================================
// Phase 1: fused QKV-proj -> QK^T -> softmax -> PV -> out-proj
// One block per n (2048 blocks), 512 threads (8 waves).
// Round-2 structure (known-good) + B-fragment double-buffering in the
// proj/out-proj loops + non-temporal input loads.
// Math note: channel/spatial attention collapse to identity
// (softmax over size-1 axes == 1), so fused = 2*input exactly.
// LDS: QB2[2][32][264]@0, KB2@16896, VT2[2][256][40]@33792,
//      SF2 f32[2][32][34]@54272, PB2[2][32][40]@58624 ; 119.5 KB, 1 blk/CU
// (register budget per wave is therefore a free ~256 -> dbuf is "free")
// =================================================================
#define QB2 0
#define KB2 16896
#define VT2 33792
#define SF2 54272
#define PB2 58624

__global__ __launch_bounds__(512, 1) void k_attn(
    const float* __restrict__ text, const float* __restrict__ graph,
    const u16* __restrict__ Wproj, const float* __restrict__ bproj,
    const u16* __restrict__ Wout, const float* __restrict__ bout,
    u16* __restrict__ attT, u16* __restrict__ attG) {
  __shared__ u16 sh[61184];
  int n = blockIdx.x;
  int tid = threadIdx.x;
  int w = tid >> 6, lane = tid & 63;
  int lr = lane & 15, kg = lane >> 4;
  int sw = w >> 2, wq = w & 3;

  // ---- A-fragments (rows mt*16+lr of 2*input, bf16), non-temporal ----
  const float* inS = sw ? graph : text;
  s16x8 aS[2][8];
#pragma unroll
  for (int mt = 0; mt < 2; ++mt)
#pragma unroll
    for (int k = 0; k < 8; ++k) {
      const float* p = inS + ((mt * 16 + lr) * 2048 + n) * 256 + k * 32 + kg * 8;
      f32x4 v0 = __builtin_nontemporal_load((const f32x4*)p);
      f32x4 v1 = __builtin_nontemporal_load((const f32x4*)p + 1);
      s16x8 t;
      t[0] = (short)f2bf(2.f * v0[0]); t[1] = (short)f2bf(2.f * v0[1]);
      t[2] = (short)f2bf(2.f * v0[2]); t[3] = (short)f2bf(2.f * v0[3]);
      t[4] = (short)f2bf(2.f * v1[0]); t[5] = (short)f2bf(2.f * v1[1]);
      t[6] = (short)f2bf(2.f * v1[2]); t[7] = (short)f2bf(2.f * v1[3]);
      aS[mt][k] = t;
    }

#define LDB_PROJ(dst, ii) { \
    const u16* wp_ = Wproj + ((wq * 12 + (ii)) * 16 + lr) * 256 + kg * 8; \
    dst[0] = *(const s16x8*)(wp_);       dst[1] = *(const s16x8*)(wp_ + 32); \
    dst[2] = *(const s16x8*)(wp_ + 64);  dst[3] = *(const s16x8*)(wp_ + 96); \
    dst[4] = *(const s16x8*)(wp_ + 128); dst[5] = *(const s16x8*)(wp_ + 160); \
    dst[6] = *(const s16x8*)(wp_ + 192); dst[7] = *(const s16x8*)(wp_ + 224); }

  // ---- QKV projection: 12 N-tiles per wave, B double-buffered ----
  {
    s16x8 bb[2][8];
    LDB_PROJ(bb[0], 0)
#pragma unroll
    for (int i = 0; i < 12; ++i) {
      const int c = i & 1, nx = c ^ 1;
      if (i < 11) { LDB_PROJ(bb[nx], i + 1) }
      f32x4 a0 = Z4, a1 = Z4;
#pragma unroll
      for (int k = 0; k < 8; ++k) {
        a0 = MFMA16(aS[0][k], bb[c][k], a0);
        a1 = MFMA16(aS[1][k], bb[c][k], a1);
      }
      int col = (wq * 12 + i) * 16 + lr;
      float bias = bproj[col];
      if (col < 512) {
        u16* base = sh + (col < 256 ? (QB2 + sw * 8448 + col)
                                    : (KB2 + sw * 8448 + col - 256));
#pragma unroll
        for (int j = 0; j < 4; ++j) {
          base[(kg * 4 + j) * 264] = f2bf(a0[j] + bias);
          base[(16 + kg * 4 + j) * 264] = f2bf(a1[j] + bias);
        }
      } else {
        u16* base = sh + VT2 + sw * 10240 + (col - 512) * 40;
#pragma unroll
        for (int j = 0; j < 4; ++j) {
          base[kg * 4 + j] = f2bf(a0[j] + bias);
          base[16 + kg * 4 + j] = f2bf(a1[j] + bias);
        }
      }
    }
  }
  __syncthreads();

  // ---- scores_s = Q_s . K_{1-s}^T / 16 ----
  {
    int s = sw, mt = (w >> 1) & 1, mh = w & 1;
    f32x4 acc = Z4;
#pragma unroll
    for (int k = 0; k < 8; ++k) {
      s16x8 qa = *(const s16x8*)(sh + QB2 + s * 8448 + (mt * 16 + lr) * 264 + k * 32 + kg * 8);
      s16x8 kb = *(const s16x8*)(sh + KB2 + (1 - s) * 8448 + (mh * 16 + lr) * 264 + k * 32 + kg * 8);
      acc = MFMA16(qa, kb, acc);
    }
    float* Sfp = (float*)(sh + SF2) + s * 1088 + mh * 16 + lr;
#pragma unroll
    for (int j = 0; j < 4; ++j)
      Sfp[(mt * 16 + kg * 4 + j) * 34] = acc[j] * 0.0625f;
  }
  __syncthreads();

  // ---- softmax over m ----
  if (tid < 64) {
    int s = tid >> 5, l = tid & 31;
    float* Sp = (float*)(sh + SF2) + s * 1088 + l * 34;
    float mx = -1e30f;
#pragma unroll
    for (int m = 0; m < 32; ++m) mx = fmaxf(mx, Sp[m]);
    float e[32]; float sum = 0.f;
#pragma unroll
    for (int m = 0; m < 32; ++m) { e[m] = __expf(Sp[m] - mx); sum += e[m]; }
    float inv = 1.f / sum;
    u16* Pp = sh + PB2 + s * 1280 + l * 40;
#pragma unroll
    for (int m = 0; m < 32; ++m) Pp[m] = f2bf(e[m] * inv);
  }
  __syncthreads();

  // ---- O_s = P_s . V_s (into QB2 region; Q dead) ----
  {
    s16x8 pa0 = *(const s16x8*)(sh + PB2 + sw * 1280 + lr * 40 + kg * 8);
    s16x8 pa1 = *(const s16x8*)(sh + PB2 + sw * 1280 + (16 + lr) * 40 + kg * 8);
#pragma unroll
    for (int i = 0; i < 4; ++i) {
      int e0 = (wq * 4 + i) * 16;
      s16x8 vb = *(const s16x8*)(sh + VT2 + sw * 10240 + (e0 + lr) * 40 + kg * 8);
      f32x4 a0 = MFMA16(pa0, vb, Z4);
      f32x4 a1 = MFMA16(pa1, vb, Z4);
      u16* base = sh + QB2 + sw * 8448 + e0 + lr;
#pragma unroll
      for (int j = 0; j < 4; ++j) {
        base[(kg * 4 + j) * 264] = f2bf(a0[j]);
        base[(16 + kg * 4 + j) * 264] = f2bf(a1[j]);
      }
    }
  }
  __syncthreads();

#define LDB_OUT(dst, ii) { \
    const u16* wp_ = Wout + ((wq * 4 + (ii)) * 16 + lr) * 256 + kg * 8; \
    dst[0] = *(const s16x8*)(wp_);       dst[1] = *(const s16x8*)(wp_ + 32); \
    dst[2] = *(const s16x8*)(wp_ + 64);  dst[3] = *(const s16x8*)(wp_ + 96); \
    dst[4] = *(const s16x8*)(wp_ + 128); dst[5] = *(const s16x8*)(wp_ + 160); \
    dst[6] = *(const s16x8*)(wp_ + 192); dst[7] = *(const s16x8*)(wp_ + 224); }

  // ---- att_s = O_s @ Wout^T + bout -> global bf16 (B dbuf) ----
  {
    s16x8 ao[2][8];
#pragma unroll
    for (int mt = 0; mt < 2; ++mt)
#pragma unroll
      for (int k = 0; k < 8; ++k)
        ao[mt][k] = *(const s16x8*)(sh + QB2 + sw * 8448 + (mt * 16 + lr) * 264 + k * 32 + kg * 8);
    u16* dst = sw ? attG : attT;
    s16x8 bb[2][8];
    LDB_OUT(bb[0], 0)
#pragma unroll
    for (int i = 0; i < 4; ++i) {
      const int c = i & 1, nx = c ^ 1;
      if (i < 3) { LDB_OUT(bb[nx], i + 1) }
      f32x4 a0 = Z4, a1 = Z4;
#pragma unroll
      for (int k = 0; k < 8; ++k) {
        a0 = MFMA16(ao[0][k], bb[c][k], a0);
        a1 = MFMA16(ao[1][k], bb[c][k], a1);
      }
      int cb = (wq * 4 + i) * 16 + lr;
      float bias = bout[cb];
#pragma unroll
      for (int j = 0; j < 4; ++j) {
        dst[((long)(kg * 4 + j) * 2048 + n) * 256 + cb] = f2bf(a0[j] + bias);
        dst[((long)(16 + kg * 4 + j) * 2048 + n) * 256 + cb] = f2bf(a1[j] + bias);
      }
    }
  }
}

// =================================================================
// Phase 2: fused H=attT*attG -> inter=H@Wlin^T -> gates -> GRU.
// 2048 blocks x 32 rows, 512 thr (8 waves); wave = 32 rows x 32 cols
// (2 M-tiles per B-fragment -> 6 loads feed 18 MFMAs), B double-buffered.
// LDS: AT[32][264]@0, AG@8448, HI@16896 = 49.5 KB.
// =================================================================
__global__ __launch_bounds__(512, 1) void k_gru(
    const u16* __restrict__ attT, const u16* __restrict__ attG,
    const u16* __restrict__ Wlin, const float* __restrict__ blin,
    const u16* __restrict__ Wih, const float* __restrict__ bih,
    const u16* __restrict__ Whh, const float* __restrict__ bhh,
    u16* __restrict__ g1, u16* __restrict__ g2) {
  __shared__ u16 sh[25344];
  const int AT = 0, AG = 8448, HI = 16896;
  int m0 = blockIdx.x * 32;
  int tid = threadIdx.x, w = tid >> 6, lane = tid & 63;
  int lr = lane & 15, kg = lane >> 4;

  // cooperative att load (coalesced, non-temporal)
  {
    int r = tid >> 4, c0 = (tid & 15) * 16;
    const u16* pt = attT + (m0 + r) * 256 + c0;
    const u16* pg = attG + (m0 + r) * 256 + c0;
    *(s16x8*)(sh + AT + r * 264 + c0) = __builtin_nontemporal_load((const s16x8*)pt);
    *(s16x8*)(sh + AT + r * 264 + c0 + 8) = __builtin_nontemporal_load((const s16x8*)(pt + 8));
    *(s16x8*)(sh + AG + r * 264 + c0) = __builtin_nontemporal_load((const s16x8*)pg);
    *(s16x8*)(sh + AG + r * 264 + c0 + 8) = __builtin_nontemporal_load((const s16x8*)(pg + 8));
  }
  __syncthreads();

  // H fragments (rows mt*16+lr)
  s16x8 aH[2][8];
#pragma unroll
  for (int mt = 0; mt < 2; ++mt)
#pragma unroll
    for (int k = 0; k < 8; ++k) {
      s16x8 t8 = *(const s16x8*)(sh + AT + (mt * 16 + lr) * 264 + k * 32 + kg * 8);
      s16x8 g8 = *(const s16x8*)(sh + AG + (mt * 16 + lr) * 264 + k * 32 + kg * 8);
      s16x8 h;
#pragma unroll
      for (int j = 0; j < 8; ++j)
        h[j] = (short)f2bf(bf2f((u16)t8[j]) * bf2f((u16)g8[j]));
      aH[mt][k] = h;
    }

  // inter = H @ Wlin^T + blin -> HI (B dbuf over k)
#pragma unroll
  for (int ic = 0; ic < 2; ++ic) {
    int col = w * 32 + ic * 16 + lr;
    const u16* wp = Wlin + col * 256 + kg * 8;
    s16x8 bw[2];
    bw[0] = *(const s16x8*)(wp);
    f32x4 a0 = Z4, a1 = Z4;
#pragma unroll
    for (int k = 0; k < 8; ++k) {
      const int c = k & 1, nx = c ^ 1;
      if (k < 7) bw[nx] = *(const s16x8*)(wp + (k + 1) * 32);
      a0 = MFMA16(aH[0][k], bw[c], a0);
      a1 = MFMA16(aH[1][k], bw[c], a1);
    }
    float bias = blin[col];
    u16* base = sh + HI + col;
#pragma unroll
    for (int j = 0; j < 4; ++j) {
      base[(kg * 4 + j) * 264] = f2bf(a0[j] + bias);
      base[(16 + kg * 4 + j) * 264] = f2bf(a1[j] + bias);
    }
  }
  __syncthreads();

#define LDGATE(slot, kk) { \
    int ko_ = (kk) * 32 + kg * 8; \
    bI[slot][0] = *(const s16x8*)(Wih + (0 * 256 + col) * 256 + ko_); \
    bI[slot][1] = *(const s16x8*)(Wih + (1 * 256 + col) * 256 + ko_); \
    bI[slot][2] = *(const s16x8*)(Wih + (2 * 256 + col) * 256 + ko_); \
    bH[slot][0] = *(const s16x8*)(Whh + (0 * 256 + col) * 256 + ko_); \
    bH[slot][1] = *(const s16x8*)(Whh + (1 * 256 + col) * 256 + ko_); \
    bH[slot][2] = *(const s16x8*)(Whh + (2 * 256 + col) * 256 + ko_); }

  // gate GEMMs (dbuf) + GRU elementwise
#pragma unroll
  for (int ic = 0; ic < 2; ++ic) {
    int col = w * 32 + ic * 16 + lr;
    f32x4 acc[3][3][2];
#pragma unroll
    for (int g = 0; g < 3; ++g)
#pragma unroll
      for (int s2 = 0; s2 < 3; ++s2) { acc[g][s2][0] = Z4; acc[g][s2][1] = Z4; }
    s16x8 bI[2][3], bH[2][3];
    LDGATE(0, 0)
#pragma unroll
    for (int k = 0; k < 8; ++k) {
      const int c = k & 1, nx = c ^ 1;
      if (k < 7) { LDGATE(nx, k + 1) }
      int ko = k * 32 + kg * 8;
      s16x8 aI0 = *(const s16x8*)(sh + HI + lr * 264 + ko);
      s16x8 aI1 = *(const s16x8*)(sh + HI + (16 + lr) * 264 + ko);
      s16x8 aT0 = *(const s16x8*)(sh + AT + lr * 264 + ko);
      s16x8 aT1 = *(const s16x8*)(sh + AT + (16 + lr) * 264 + ko);
      s16x8 aG0 = *(const s16x8*)(sh + AG + lr * 264 + ko);
      s16x8 aG1 = *(const s16x8*)(sh + AG + (16 + lr) * 264 + ko);
#pragma unroll
      for (int g = 0; g < 3; ++g) {
        acc[g][0][0] = MFMA16(aI0, bI[c][g], acc[g][0][0]);
        acc[g][0][1] = MFMA16(aI1, bI[c][g], acc[g][0][1]);
        acc[g][1][0] = MFMA16(aT0, bH[c][g], acc[g][1][0]);
        acc[g][1][1] = MFMA16(aT1, bH[c][g], acc[g][1][1]);
        acc[g][2][0] = MFMA16(aG0, bH[c][g], acc[g][2][0]);
        acc[g][2][1] = MFMA16(aG1, bH[c][g], acc[g][2][1]);
      }
    }
    float bir = bih[col], biz = bih[col + 256], bin_ = bih[col + 512];
    float bhr = bhh[col], bhz = bhh[col + 256], bhn = bhh[col + 512];
#pragma unroll
    for (int mt = 0; mt < 2; ++mt)
#pragma unroll
      for (int j = 0; j < 4; ++j) {
        int row = mt * 16 + kg * 4 + j;
        long off = (long)(m0 + row) * 256 + col;
        float hT = bf2f(sh[AT + row * 264 + col]);
        float hG = bf2f(sh[AG + row * 264 + col]);
        float ir = acc[0][0][mt][j] + bir;
        float iz = acc[1][0][mt][j] + biz;
        float inn = acc[2][0][mt][j] + bin_;
        float r1 = sigmoidf_(ir + acc[0][1][mt][j] + bhr);
        float z1 = sigmoidf_(iz + acc[1][1][mt][j] + bhz);
        float n1 = tanhf_(inn + r1 * (acc[2][1][mt][j] + bhn));
        g1[off] = f2bf((1.f - z1) * n1 + z1 * hT);
        float r2 = sigmoidf_(ir + acc[0][2][mt][j] + bhr);
        float z2 = sigmoidf_(iz + acc[1][2][mt][j] + bhz);
        float n2 = tanhf_(inn + r2 * (acc[2][2][mt][j] + bhn));
        g2[off] = f2bf((1.f - z2) * n2 + z2 * hG);
      }
  }
}

// =================================================================
// Phase 3: out = relu(conv7x7(g1)+b) + relu(conv7x7(g2)+b), f32 out
// =================================================================
__global__ __launch_bounds__(256) void k_conv(
    const u16* __restrict__ g1, const u16* __restrict__ g2,
    const float* __restrict__ wss, const float* __restrict__ bss,
    float* __restrict__ out) {
  __shared__ float s1[38][73];
  __shared__ float s2[38][73];
  int et = blockIdx.x, st = blockIdx.y, b = blockIdx.z;
  int s0 = st * 32, e0 = et * 64;
  int tid = threadIdx.x;
  for (int idx = tid; idx < 38 * 70; idx += 256) {
    int r = idx / 70, c = idx % 70;
    int s = s0 + r - 3, e = e0 + c - 3;
    float v1 = 0.f, v2 = 0.f;
    if (s >= 0 && s < 2048 && e >= 0 && e < 256) {
      long off = ((long)b * 2048 + s) * 256 + e;
      v1 = bf2f(g1[off]); v2 = bf2f(g2[off]);
    }
    s1[r][c] = v1; s2[r][c] = v2;
  }
  __syncthreads();
  float bias = bss[0];
  int oy = tid >> 3, ox = (tid & 7) * 8;
  float a1[8] = {0.f, 0.f, 0.f, 0.f, 0.f, 0.f, 0.f, 0.f};
  float a2[8] = {0.f, 0.f, 0.f, 0.f, 0.f, 0.f, 0.f, 0.f};
#pragma unroll
  for (int ky = 0; ky < 7; ++ky) {
    float wr[7];
#pragma unroll
    for (int kx = 0; kx < 7; ++kx) wr[kx] = wss[ky * 7 + kx];
    float r1[14], r2[14];
#pragma unroll
    for (int j = 0; j < 14; ++j) { r1[j] = s1[oy + ky][ox + j]; r2[j] = s2[oy + ky][ox + j]; }
#pragma unroll
    for (int x = 0; x < 8; ++x)
#pragma unroll
      for (int kx = 0; kx < 7; ++kx) {
        a1[x] += r1[x + kx] * wr[kx];
        a2[x] += r2[x + kx] * wr[kx];
      }
  }
  long obase = ((long)b * 2048 + s0 + oy) * 256 + e0 + ox;
  f32x4 o0, o1;
#pragma unroll
  for (int x = 0; x < 4; ++x) {
    o0[x] = fmaxf(a1[x] + bias, 0.f) + fmaxf(a2[x] + bias, 0.f);
    o1[x] = fmaxf(a1[x + 4] + bias, 0.f) + fmaxf(a2[x + 4] + bias, 0.f);
  }
  *(f32x4*)(out + obase) = o0;
  *(f32x4*)(out + obase + 4) = o1;
}

extern "C" void kernel_launch(void* const* d_in, const int* in_sizes, int n_in,
                              void* d_out, int out_size, void* d_ws, size_t ws_size,
                              hipStream_t stream) {
  const float* text = (const float*)d_in[0];
  const float* graph = (const float*)d_in[1];
  // d_in[2..7] (avg_*/max_*/sp_*) are mathematically dead:
  // softmax over size-1 axes == 1 -> fused = 2*input exactly.
  const float* in_proj_w = (const float*)d_in[8];
  const float* in_proj_b = (const float*)d_in[9];
  const float* out_w = (const float*)d_in[10];
  const float* out_b = (const float*)d_in[11];
  const float* lin_w = (const float*)d_in[12];
  const float* lin_b = (const float*)d_in[13];
  const float* w_ih = (const float*)d_in[14];
  const float* w_hh = (const float*)d_in[15];
  const float* b_ih = (const float*)d_in[16];
  const float* b_hh = (const float*)d_in[17];
  const float* ssf_w = (const float*)d_in[18];
  const float* ssf_b = (const float*)d_in[19];

  // ws: g1 (32MB) | g2 (32MB) | bf16 weights (~1.4MB)
  u16* g1 = (u16*)d_ws;
  u16* g2 = g1 + 16777216;
  u16* Wall = g2 + 16777216;
  u16* Wproj = Wall;
  u16* Wout = Wall + 196608;
  u16* Wlin = Wall + 262144;
  u16* Wih = Wall + 327680;
  u16* Whh = Wall + 524288;

  // d_out (64MB f32) doubles as bf16 scratch for attT/attG;
  // k_conv fully rewrites it as f32 at the end.
  u16* attT = (u16*)d_out;
  u16* attG = attT + 16777216;

  k_wconv<<<2816, 256, 0, stream>>>(in_proj_w, out_w, lin_w, w_ih, w_hh, Wall);

  k_attn<<<2048, 512, 0, stream>>>(text, graph, Wproj, in_proj_b, Wout, out_b, attT, attG);
  k_gru<<<2048, 512, 0, stream>>>(attT, attG, Wlin, lin_b, Wih, b_ih, Whh, b_hh, g1, g2);
  k_conv<<<dim3(4, 64, 32), 256, 0, stream>>>(g1, g2, ssf_w, ssf_b, (float*)d_out);
}

// Round 6
// 637.823 us; speedup vs baseline: 1.5669x; 1.1561x over previous
//
#include <hip/hip_runtime.h>

typedef unsigned short u16;
typedef short s16x8 __attribute__((ext_vector_type(8)));
typedef float f32x4 __attribute__((ext_vector_type(4)));

#define DEVI static __device__ __forceinline__
#define MFMA16(A, B, C) __builtin_amdgcn_mfma_f32_16x16x32_bf16(A, B, C, 0, 0, 0)
#define Z4 ((f32x4){0.f, 0.f, 0.f, 0.f})

DEVI float bf2f(u16 u) {
  unsigned int x = ((unsigned int)u) << 16;
  float f; __builtin_memcpy(&f, &x, 4); return f;
}
DEVI u16 f2bf(float f) {
  unsigned int u; __builtin_memcpy(&u, &f, 4);
  u += 0x7fffu + ((u >> 16) & 1u);
  return (u16)(u >> 16);
}
DEVI float sigmoidf_(float x) { return 1.0f / (1.0f + __expf(-x)); }
DEVI float tanhf_(float x) { return 1.0f - 2.0f / (__expf(2.0f * x) + 1.0f); }

// ---------------- merged weight f32 -> bf16 ----------------
__global__ void k_wconv(const float* __restrict__ w0, const float* __restrict__ w1,
                        const float* __restrict__ w2, const float* __restrict__ w3,
                        const float* __restrict__ w4, u16* __restrict__ out) {
  int i = blockIdx.x * 256 + threadIdx.x;
  if (i >= 720896) return;
  const float* src; int off;
  if (i < 196608) { src = w0; off = i; }
  else if (i < 262144) { src = w1; off = i - 196608; }
  else if (i < 327680) { src = w2; off = i - 262144; }
  else if (i < 524288) { src = w3; off = i - 327680; }
  else { src = w4; off = i - 524288; }
  out[i] = f2bf(src[off]);
}

// =================================================================
// k_tr: (b,s,e) f32 -> (s,b,e) bf16 with the 2x fused-identity factor
// folded in. e is contiguous in both layouts -> both sides coalesced.
// One thread per 8 elems. 2 sides x 16M elems / 8 = 2^22 threads.
// =================================================================
__global__ void k_tr(const float* __restrict__ text, const float* __restrict__ graph,
                     u16* __restrict__ T2T, u16* __restrict__ T2G) {
  long idx = (long)blockIdx.x * 256 + threadIdx.x;
  int side = (int)(idx >> 21);
  long r = (idx >> 5) & 65535;   // input row = b*2048 + s
  int c8 = (int)(idx & 31);
  long b = r >> 11, s = r & 2047;
  const float* src = (side ? graph : text) + r * 256 + c8 * 8;
  u16* dst = (side ? T2G : T2T) + ((s << 5) + b) * 256 + c8 * 8;
  f32x4 v0 = *(const f32x4*)src;
  f32x4 v1 = *(const f32x4*)(src + 4);
  s16x8 t;
  t[0] = (short)f2bf(2.f * v0[0]); t[1] = (short)f2bf(2.f * v0[1]);
  t[2] = (short)f2bf(2.f * v0[2]); t[3] = (short)f2bf(2.f * v0[3]);
  t[4] = (short)f2bf(2.f * v1[0]); t[5] = (short)f2bf(2.f * v1[1]);
  t[6] = (short)f2bf(2.f * v1[2]); t[7] = (short)f2bf(2.f * v1[3]);
  *(s16x8*)dst = t;
}

// =================================================================
// Phase 1: per-(n,side) block: K/Q/V proj -> QK^T -> softmax -> PV
// -> out-proj. 4096 blocks x 256 thr (4 waves).
// Math note: channel/spatial attention collapse to identity
// (softmax over size-1 axes == 1), so fused = 2*input exactly.
// All global reads/writes contiguous (panels pre-transposed by k_tr;
// output staged through LDS into 512B row chunks).
// LDS overlay (u16 offsets), peak 37184 u16 = 72.6 KB -> 2 blocks/CU:
//   AO[32][264]@0        own-side A panel  (dead after aof regs load)
//   AX[32][264]@8448     other-side A      (dead after axf regs load)
//   KB[32][264]@16896    K                 (dead after scores)
//   QB[32][264]@25344    Q                 (dead after scores)
//   SF f32[32][33]@33792 scores            (dead after softmax)
//   PB[32][40]@35904     softmax P
//   VT[256][40]@8448     V^T  (overlays AX + KB head, written post-scores)
//   OB[32][264]@25344    O    (overlays QB)
//   ST[32][264]@16896    out staging (overlays KB/VT tail, post-PV)
// =================================================================
#define AOo 0
#define AXo 8448
#define KBo 16896
#define QBo 25344
#define SFo 33792
#define PBo 35904
#define VTo 8448
#define OBo 25344
#define STo 16896

__global__ __launch_bounds__(256, 2) void k_attn(
    const u16* __restrict__ T2T, const u16* __restrict__ T2G,
    const u16* __restrict__ Wproj, const float* __restrict__ bproj,
    const u16* __restrict__ Wout, const float* __restrict__ bout,
    u16* __restrict__ attT, u16* __restrict__ attG) {
  __shared__ u16 sh[37184];
  int n = blockIdx.x, s = blockIdx.y;
  const u16* pown = (s ? T2G : T2T) + n * 8192;
  const u16* poth = (s ? T2T : T2G) + n * 8192;
  u16* dst = s ? attG : attT;
  int tid = threadIdx.x, w = tid >> 6, lane = tid & 63;
  int lr = lane & 15, kg = lane >> 4;

  // ---- ph1: cooperative 16KB panel loads (coalesced) ----
  {
    int r = tid >> 3, c0 = (tid & 7) * 32;
    const u16* so = pown + r * 256 + c0;
    const u16* sx = poth + r * 256 + c0;
    u16* d0 = sh + AOo + r * 264 + c0;
    u16* d1 = sh + AXo + r * 264 + c0;
#pragma unroll
    for (int j = 0; j < 4; ++j) {
      *(s16x8*)(d0 + j * 8) = *(const s16x8*)(so + j * 8);
      *(s16x8*)(d1 + j * 8) = *(const s16x8*)(sx + j * 8);
    }
  }
  __syncthreads();

  s16x8 af[2][8];  // A fragments (AX for K, then AO for Q/V)

  // ---- ph2a: K-proj from other-side panel (cols 256..511) ----
#pragma unroll
  for (int mt = 0; mt < 2; ++mt)
#pragma unroll
    for (int k = 0; k < 8; ++k)
      af[mt][k] = *(const s16x8*)(sh + AXo + (mt * 16 + lr) * 264 + k * 32 + kg * 8);
  for (int i = 0; i < 4; ++i) {
    int colk = 256 + (w * 4 + i) * 16 + lr;
    const u16* wp = Wproj + colk * 256 + kg * 8;
    s16x8 b[8];
#pragma unroll
    for (int k = 0; k < 8; ++k) b[k] = *(const s16x8*)(wp + k * 32);
    f32x4 a0 = Z4, a1 = Z4;
#pragma unroll
    for (int k = 0; k < 8; ++k) {
      a0 = MFMA16(af[0][k], b[k], a0);
      a1 = MFMA16(af[1][k], b[k], a1);
    }
    float bias = bproj[colk];
    u16* base = sh + KBo + (colk - 256);
#pragma unroll
    for (int j = 0; j < 4; ++j) {
      base[(kg * 4 + j) * 264] = f2bf(a0[j] + bias);
      base[(16 + kg * 4 + j) * 264] = f2bf(a1[j] + bias);
    }
  }

  // ---- ph2b: Q-proj from own-side panel (cols 0..255) ----
#pragma unroll
  for (int mt = 0; mt < 2; ++mt)
#pragma unroll
    for (int k = 0; k < 8; ++k)
      af[mt][k] = *(const s16x8*)(sh + AOo + (mt * 16 + lr) * 264 + k * 32 + kg * 8);
  for (int i = 0; i < 4; ++i) {
    int colq = (w * 4 + i) * 16 + lr;
    const u16* wp = Wproj + colq * 256 + kg * 8;
    s16x8 b[8];
#pragma unroll
    for (int k = 0; k < 8; ++k) b[k] = *(const s16x8*)(wp + k * 32);
    f32x4 a0 = Z4, a1 = Z4;
#pragma unroll
    for (int k = 0; k < 8; ++k) {
      a0 = MFMA16(af[0][k], b[k], a0);
      a1 = MFMA16(af[1][k], b[k], a1);
    }
    float bias = bproj[colq];
    u16* base = sh + QBo + colq;
#pragma unroll
    for (int j = 0; j < 4; ++j) {
      base[(kg * 4 + j) * 264] = f2bf(a0[j] + bias);
      base[(16 + kg * 4 + j) * 264] = f2bf(a1[j] + bias);
    }
  }
  __syncthreads();

  // ---- ph3: scores S[l][m] = Q.K^T / 16 (wave -> one 16x16 tile) ----
  {
    int mt = w >> 1, nt = w & 1;
    f32x4 acc = Z4;
#pragma unroll
    for (int k = 0; k < 8; ++k) {
      s16x8 qa = *(const s16x8*)(sh + QBo + (mt * 16 + lr) * 264 + k * 32 + kg * 8);
      s16x8 kb = *(const s16x8*)(sh + KBo + (nt * 16 + lr) * 264 + k * 32 + kg * 8);
      acc = MFMA16(qa, kb, acc);
    }
    float* Sf = (float*)(sh + SFo);
#pragma unroll
    for (int j = 0; j < 4; ++j)
      Sf[(mt * 16 + kg * 4 + j) * 33 + nt * 16 + lr] = acc[j] * 0.0625f;
  }
  __syncthreads();

  // ---- ph4: V-proj (cols 512..767, af=AO still live) + softmax ----
  for (int i = 0; i < 4; ++i) {
    int colv = 512 + (w * 4 + i) * 16 + lr;
    const u16* wp = Wproj + colv * 256 + kg * 8;
    s16x8 b[8];
#pragma unroll
    for (int k = 0; k < 8; ++k) b[k] = *(const s16x8*)(wp + k * 32);
    f32x4 a0 = Z4, a1 = Z4;
#pragma unroll
    for (int k = 0; k < 8; ++k) {
      a0 = MFMA16(af[0][k], b[k], a0);
      a1 = MFMA16(af[1][k], b[k], a1);
    }
    float bias = bproj[colv];
    u16* base = sh + VTo + (colv - 512) * 40;
#pragma unroll
    for (int j = 0; j < 4; ++j) {
      base[kg * 4 + j] = f2bf(a0[j] + bias);
      base[16 + kg * 4 + j] = f2bf(a1[j] + bias);
    }
  }
  if (tid < 32) {
    float* Sp = (float*)(sh + SFo) + tid * 33;
    float mx = -1e30f;
#pragma unroll
    for (int m = 0; m < 32; ++m) mx = fmaxf(mx, Sp[m]);
    float e[32]; float sum = 0.f;
#pragma unroll
    for (int m = 0; m < 32; ++m) { e[m] = __expf(Sp[m] - mx); sum += e[m]; }
    float inv = 1.f / sum;
    u16* Pp = sh + PBo + tid * 40;
#pragma unroll
    for (int m = 0; m < 32; ++m) Pp[m] = f2bf(e[m] * inv);
  }
  __syncthreads();

  // ---- ph5: PV: O = P.V -> OB (over dead QB) ----
  {
    s16x8 pa0 = *(const s16x8*)(sh + PBo + lr * 40 + kg * 8);
    s16x8 pa1 = *(const s16x8*)(sh + PBo + (16 + lr) * 40 + kg * 8);
#pragma unroll
    for (int i = 0; i < 4; ++i) {
      int e0 = (w * 4 + i) * 16;
      s16x8 vb = *(const s16x8*)(sh + VTo + (e0 + lr) * 40 + kg * 8);
      f32x4 a0 = MFMA16(pa0, vb, Z4);
      f32x4 a1 = MFMA16(pa1, vb, Z4);
      u16* base = sh + OBo + e0 + lr;
#pragma unroll
      for (int j = 0; j < 4; ++j) {
        base[(kg * 4 + j) * 264] = f2bf(a0[j]);
        base[(16 + kg * 4 + j) * 264] = f2bf(a1[j]);
      }
    }
  }
  __syncthreads();

  // ---- ph6: out-proj -> ST staging -> coalesced row writes ----
  {
    s16x8 ao[2][8];
#pragma unroll
    for (int mt = 0; mt < 2; ++mt)
#pragma unroll
      for (int k = 0; k < 8; ++k)
        ao[mt][k] = *(const s16x8*)(sh + OBo + (mt * 16 + lr) * 264 + k * 32 + kg * 8);
    for (int i = 0; i < 4; ++i) {
      int cb = (w * 4 + i) * 16 + lr;
      const u16* wp = Wout + cb * 256 + kg * 8;
      s16x8 b[8];
#pragma unroll
      for (int k = 0; k < 8; ++k) b[k] = *(const s16x8*)(wp + k * 32);
      f32x4 a0 = Z4, a1 = Z4;
#pragma unroll
      for (int k = 0; k < 8; ++k) {
        a0 = MFMA16(ao[0][k], b[k], a0);
        a1 = MFMA16(ao[1][k], b[k], a1);
      }
      float bias = bout[cb];
      u16* base = sh + STo + cb;
#pragma unroll
      for (int j = 0; j < 4; ++j) {
        base[(kg * 4 + j) * 264] = f2bf(a0[j] + bias);
        base[(16 + kg * 4 + j) * 264] = f2bf(a1[j] + bias);
      }
    }
  }
  __syncthreads();
  {
    int r = tid >> 3, c0 = (tid & 7) * 32;
    u16* dr = dst + ((long)r * 2048 + n) * 256 + c0;
#pragma unroll
    for (int j = 0; j < 4; ++j)
      *(s16x8*)(dr + j * 8) = *(const s16x8*)(sh + STo + r * 264 + c0 + j * 8);
  }
}

// =================================================================
// Phase 2: fused H=attT*attG -> inter=H@Wlin^T -> gates -> GRU.
// 2048 blocks x 32 rows, 512 thr (8 waves); wave = 32 rows x 32 cols
// (2 M-tiles per B-fragment), B double-buffered. (unchanged, round 5)
// =================================================================
__global__ __launch_bounds__(512, 1) void k_gru(
    const u16* __restrict__ attT, const u16* __restrict__ attG,
    const u16* __restrict__ Wlin, const float* __restrict__ blin,
    const u16* __restrict__ Wih, const float* __restrict__ bih,
    const u16* __restrict__ Whh, const float* __restrict__ bhh,
    u16* __restrict__ g1, u16* __restrict__ g2) {
  __shared__ u16 sh[25344];
  const int AT = 0, AG = 8448, HI = 16896;
  int m0 = blockIdx.x * 32;
  int tid = threadIdx.x, w = tid >> 6, lane = tid & 63;
  int lr = lane & 15, kg = lane >> 4;

  {
    int r = tid >> 4, c0 = (tid & 15) * 16;
    const u16* pt = attT + (m0 + r) * 256 + c0;
    const u16* pg = attG + (m0 + r) * 256 + c0;
    *(s16x8*)(sh + AT + r * 264 + c0) = __builtin_nontemporal_load((const s16x8*)pt);
    *(s16x8*)(sh + AT + r * 264 + c0 + 8) = __builtin_nontemporal_load((const s16x8*)(pt + 8));
    *(s16x8*)(sh + AG + r * 264 + c0) = __builtin_nontemporal_load((const s16x8*)pg);
    *(s16x8*)(sh + AG + r * 264 + c0 + 8) = __builtin_nontemporal_load((const s16x8*)(pg + 8));
  }
  __syncthreads();

  s16x8 aH[2][8];
#pragma unroll
  for (int mt = 0; mt < 2; ++mt)
#pragma unroll
    for (int k = 0; k < 8; ++k) {
      s16x8 t8 = *(const s16x8*)(sh + AT + (mt * 16 + lr) * 264 + k * 32 + kg * 8);
      s16x8 g8 = *(const s16x8*)(sh + AG + (mt * 16 + lr) * 264 + k * 32 + kg * 8);
      s16x8 h;
#pragma unroll
      for (int j = 0; j < 8; ++j)
        h[j] = (short)f2bf(bf2f((u16)t8[j]) * bf2f((u16)g8[j]));
      aH[mt][k] = h;
    }

#pragma unroll
  for (int ic = 0; ic < 2; ++ic) {
    int col = w * 32 + ic * 16 + lr;
    const u16* wp = Wlin + col * 256 + kg * 8;
    s16x8 bw[2];
    bw[0] = *(const s16x8*)(wp);
    f32x4 a0 = Z4, a1 = Z4;
#pragma unroll
    for (int k = 0; k < 8; ++k) {
      const int c = k & 1, nx = c ^ 1;
      if (k < 7) bw[nx] = *(const s16x8*)(wp + (k + 1) * 32);
      a0 = MFMA16(aH[0][k], bw[c], a0);
      a1 = MFMA16(aH[1][k], bw[c], a1);
    }
    float bias = blin[col];
    u16* base = sh + HI + col;
#pragma unroll
    for (int j = 0; j < 4; ++j) {
      base[(kg * 4 + j) * 264] = f2bf(a0[j] + bias);
      base[(16 + kg * 4 + j) * 264] = f2bf(a1[j] + bias);
    }
  }
  __syncthreads();

#define LDGATE(slot, kk) { \
    int ko_ = (kk) * 32 + kg * 8; \
    bI[slot][0] = *(const s16x8*)(Wih + (0 * 256 + col) * 256 + ko_); \
    bI[slot][1] = *(const s16x8*)(Wih + (1 * 256 + col) * 256 + ko_); \
    bI[slot][2] = *(const s16x8*)(Wih + (2 * 256 + col) * 256 + ko_); \
    bH[slot][0] = *(const s16x8*)(Whh + (0 * 256 + col) * 256 + ko_); \
    bH[slot][1] = *(const s16x8*)(Whh + (1 * 256 + col) * 256 + ko_); \
    bH[slot][2] = *(const s16x8*)(Whh + (2 * 256 + col) * 256 + ko_); }

#pragma unroll
  for (int ic = 0; ic < 2; ++ic) {
    int col = w * 32 + ic * 16 + lr;
    f32x4 acc[3][3][2];
#pragma unroll
    for (int g = 0; g < 3; ++g)
#pragma unroll
      for (int s2 = 0; s2 < 3; ++s2) { acc[g][s2][0] = Z4; acc[g][s2][1] = Z4; }
    s16x8 bI[2][3], bH[2][3];
    LDGATE(0, 0)
#pragma unroll
    for (int k = 0; k < 8; ++k) {
      const int c = k & 1, nx = c ^ 1;
      if (k < 7) { LDGATE(nx, k + 1) }
      int ko = k * 32 + kg * 8;
      s16x8 aI0 = *(const s16x8*)(sh + HI + lr * 264 + ko);
      s16x8 aI1 = *(const s16x8*)(sh + HI + (16 + lr) * 264 + ko);
      s16x8 aT0 = *(const s16x8*)(sh + AT + lr * 264 + ko);
      s16x8 aT1 = *(const s16x8*)(sh + AT + (16 + lr) * 264 + ko);
      s16x8 aG0 = *(const s16x8*)(sh + AG + lr * 264 + ko);
      s16x8 aG1 = *(const s16x8*)(sh + AG + (16 + lr) * 264 + ko);
#pragma unroll
      for (int g = 0; g < 3; ++g) {
        acc[g][0][0] = MFMA16(aI0, bI[c][g], acc[g][0][0]);
        acc[g][0][1] = MFMA16(aI1, bI[c][g], acc[g][0][1]);
        acc[g][1][0] = MFMA16(aT0, bH[c][g], acc[g][1][0]);
        acc[g][1][1] = MFMA16(aT1, bH[c][g], acc[g][1][1]);
        acc[g][2][0] = MFMA16(aG0, bH[c][g], acc[g][2][0]);
        acc[g][2][1] = MFMA16(aG1, bH[c][g], acc[g][2][1]);
      }
    }
    float bir = bih[col], biz = bih[col + 256], bin_ = bih[col + 512];
    float bhr = bhh[col], bhz = bhh[col + 256], bhn = bhh[col + 512];
#pragma unroll
    for (int mt = 0; mt < 2; ++mt)
#pragma unroll
      for (int j = 0; j < 4; ++j) {
        int row = mt * 16 + kg * 4 + j;
        long off = (long)(m0 + row) * 256 + col;
        float hT = bf2f(sh[AT + row * 264 + col]);
        float hG = bf2f(sh[AG + row * 264 + col]);
        float ir = acc[0][0][mt][j] + bir;
        float iz = acc[1][0][mt][j] + biz;
        float inn = acc[2][0][mt][j] + bin_;
        float r1 = sigmoidf_(ir + acc[0][1][mt][j] + bhr);
        float z1 = sigmoidf_(iz + acc[1][1][mt][j] + bhz);
        float n1 = tanhf_(inn + r1 * (acc[2][1][mt][j] + bhn));
        g1[off] = f2bf((1.f - z1) * n1 + z1 * hT);
        float r2 = sigmoidf_(ir + acc[0][2][mt][j] + bhr);
        float z2 = sigmoidf_(iz + acc[1][2][mt][j] + bhz);
        float n2 = tanhf_(inn + r2 * (acc[2][2][mt][j] + bhn));
        g2[off] = f2bf((1.f - z2) * n2 + z2 * hG);
      }
  }
}

// =================================================================
// Phase 3: out = relu(conv7x7(g1)+b) + relu(conv7x7(g2)+b), f32 out
// =================================================================
__global__ __launch_bounds__(256) void k_conv(
    const u16* __restrict__ g1, const u16* __restrict__ g2,
    const float* __restrict__ wss, const float* __restrict__ bss,
    float* __restrict__ out) {
  __shared__ float s1[38][73];
  __shared__ float s2[38][73];
  int et = blockIdx.x, st = blockIdx.y, b = blockIdx.z;
  int s0 = st * 32, e0 = et * 64;
  int tid = threadIdx.x;
  for (int idx = tid; idx < 38 * 70; idx += 256) {
    int r = idx / 70, c = idx % 70;
    int s = s0 + r - 3, e = e0 + c - 3;
    float v1 = 0.f, v2 = 0.f;
    if (s >= 0 && s < 2048 && e >= 0 && e < 256) {
      long off = ((long)b * 2048 + s) * 256 + e;
      v1 = bf2f(g1[off]); v2 = bf2f(g2[off]);
    }
    s1[r][c] = v1; s2[r][c] = v2;
  }
  __syncthreads();
  float bias = bss[0];
  int oy = tid >> 3, ox = (tid & 7) * 8;
  float a1[8] = {0.f, 0.f, 0.f, 0.f, 0.f, 0.f, 0.f, 0.f};
  float a2[8] = {0.f, 0.f, 0.f, 0.f, 0.f, 0.f, 0.f, 0.f};
#pragma unroll
  for (int ky = 0; ky < 7; ++ky) {
    float wr[7];
#pragma unroll
    for (int kx = 0; kx < 7; ++kx) wr[kx] = wss[ky * 7 + kx];
    float r1[14], r2[14];
#pragma unroll
    for (int j = 0; j < 14; ++j) { r1[j] = s1[oy + ky][ox + j]; r2[j] = s2[oy + ky][ox + j]; }
#pragma unroll
    for (int x = 0; x < 8; ++x)
#pragma unroll
      for (int kx = 0; kx < 7; ++kx) {
        a1[x] += r1[x + kx] * wr[kx];
        a2[x] += r2[x + kx] * wr[kx];
      }
  }
  long obase = ((long)b * 2048 + s0 + oy) * 256 + e0 + ox;
  f32x4 o0, o1;
#pragma unroll
  for (int x = 0; x < 4; ++x) {
    o0[x] = fmaxf(a1[x] + bias, 0.f) + fmaxf(a2[x] + bias, 0.f);
    o1[x] = fmaxf(a1[x + 4] + bias, 0.f) + fmaxf(a2[x + 4] + bias, 0.f);
  }
  *(f32x4*)(out + obase) = o0;
  *(f32x4*)(out + obase + 4) = o1;
}

extern "C" void kernel_launch(void* const* d_in, const int* in_sizes, int n_in,
                              void* d_out, int out_size, void* d_ws, size_t ws_size,
                              hipStream_t stream) {
  const float* text = (const float*)d_in[0];
  const float* graph = (const float*)d_in[1];
  // d_in[2..7] (avg_*/max_*/sp_*) are mathematically dead:
  // softmax over size-1 axes == 1 -> fused = 2*input exactly.
  const float* in_proj_w = (const float*)d_in[8];
  const float* in_proj_b = (const float*)d_in[9];
  const float* out_w = (const float*)d_in[10];
  const float* out_b = (const float*)d_in[11];
  const float* lin_w = (const float*)d_in[12];
  const float* lin_b = (const float*)d_in[13];
  const float* w_ih = (const float*)d_in[14];
  const float* w_hh = (const float*)d_in[15];
  const float* b_ih = (const float*)d_in[16];
  const float* b_hh = (const float*)d_in[17];
  const float* ssf_w = (const float*)d_in[18];
  const float* ssf_b = (const float*)d_in[19];

  // ws: g1 (32MB) | g2 (32MB) | bf16 weights (~1.4MB)
  // T2T/T2G (pre-transposed inputs) ALIAS g1/g2: T2 is written by k_tr,
  // read by k_attn; g1/g2 are written by k_gru (after attn) and read by
  // k_conv -> lifetimes disjoint.
  u16* g1 = (u16*)d_ws;
  u16* g2 = g1 + 16777216;
  u16* T2T = g1;
  u16* T2G = g2;
  u16* Wall = g2 + 16777216;
  u16* Wproj = Wall;
  u16* Wout = Wall + 196608;
  u16* Wlin = Wall + 262144;
  u16* Wih = Wall + 327680;
  u16* Whh = Wall + 524288;

  // d_out (64MB f32) doubles as bf16 scratch for attT/attG;
  // k_conv fully rewrites it as f32 at the end.
  u16* attT = (u16*)d_out;
  u16* attG = attT + 16777216;

  k_wconv<<<2816, 256, 0, stream>>>(in_proj_w, out_w, lin_w, w_ih, w_hh, Wall);
  k_tr<<<16384, 256, 0, stream>>>(text, graph, T2T, T2G);

  k_attn<<<dim3(2048, 2), 256, 0, stream>>>(T2T, T2G, Wproj, in_proj_b, Wout, out_b, attT, attG);
  k_gru<<<2048, 512, 0, stream>>>(attT, attG, Wlin, lin_b, Wih, b_ih, Whh, b_hh, g1, g2);
  k_conv<<<dim3(4, 64, 32), 256, 0, stream>>>(g1, g2, ssf_w, ssf_b, (float*)d_out);
}